// Round 8
// baseline (174.624 us; speedup 1.0000x reference)
//
#include <hip/hip_runtime.h>
#include <hip/hip_bf16.h>

// Flash-attention fwd, block-causal packed docs. fp32 HBM, bf16 MFMA.
// B=1, H=8, D=128. 4 waves/block, BR=64, BC=64, grid 512.
// R8: (1) balanced qb permutation -- blocks b and b+256 have ntiles summing
// to 17 under breadth-first round-robin dispatch; (2) single-buffered
// sK/sVT (prefetch regs are buffer 2), 2 barriers/tile, LDS 43 KB ->
// 3 blocks/CU; (3) packed v_cvt_pk_bf16_f32 staging converts.

#define HD 128
#define BR 64
#define BC 64
#define KSTR 136     // bf16 per sK row: 272 B
#define VSTR 33      // dwords per sVT row (32 key-pair dwords + 1 pad; odd)
#define PSTR 68      // bf16 per sP row: 136 B

typedef __attribute__((ext_vector_type(8))) short short8;
typedef __attribute__((ext_vector_type(4))) short short4v;
typedef __attribute__((ext_vector_type(4))) float floatx4;

__device__ inline unsigned packbf2(float lo, float hi) {
    __hip_bfloat162 h2 = __float22bfloat162_rn(make_float2(lo, hi));
    return *reinterpret_cast<unsigned*>(&h2);   // low16 = lo, high16 = hi
}
__device__ inline short bfs(float f) {
    __hip_bfloat16 b = __float2bfloat16(f);
    return *reinterpret_cast<short*>(&b);
}

union F4 { float4 v; float f[4]; };

__global__ __launch_bounds__(256, 3) void fa_fwd(
    const float* __restrict__ Q,
    const float* __restrict__ K,
    const float* __restrict__ V,
    const int* __restrict__ cu_seqlens, int n_cu,
    float* __restrict__ O,
    int S)
{
    __shared__ alignas(16) __hip_bfloat16 sK[BC * KSTR];     // 17408 B
    __shared__ alignas(16) unsigned int   sVT[HD * VSTR];    // 16896 B
    __shared__ alignas(16) __hip_bfloat16 sP[4][16 * PSTR];  //  8704 B

    const int tid  = threadIdx.x;
    const int wave = tid >> 6;
    const int lane = tid & 63;
    const int quad = lane >> 4;
    const int l16  = lane & 15;

    // K staging coords
    const int dblk = tid & 31;      // d = 4*dblk
    const int trow = tid >> 5;      // 0..7
    // V staging coords: one d-row per thread
    const int vd    = tid & 127;
    const int vhalf = tid >> 7;

    const int nqb = S / BR;
    const int h   = blockIdx.x & 7;
    const int g   = (int)(blockIdx.x >> 3);   // 0..nqb-1
    int qb;
    if (nqb == 64) {
        // balanced pairing for 4 docs x 16 q-blocks: pair (g, g+32) sums 17
        if (g < 32) qb = (g >> 4) * 16 + (15 - (g & 15));        // docs 0,1 desc
        else        qb = 32 + (((g - 32) >> 4) * 16) + (g & 15); // docs 2,3 asc
    } else {
        qb = nqb - 1 - g;
    }
    const int q0  = qb * BR;
    const int qw  = q0 + wave * 16;

    const size_t hoff = (size_t)h * S * HD;
    const float* Qh = Q + hoff;
    const float* Kh = K + hoff;
    const float* Vh = V + hoff;
    float*       Oh = O + hoff;

    // ---- per-row doc starts ----
    int doc_start[4];
    #pragma unroll
    for (int r = 0; r < 4; ++r) {
        const int q = qw + quad * 4 + r;
        int dsr = 0;
        for (int i = 0; i < n_cu; ++i) {
            int c = cu_seqlens[i];
            if (c <= q) dsr = c;
        }
        doc_start[r] = dsr;
    }
    int blk_ds = 0;
    for (int i = 0; i < n_cu; ++i) {
        int c = cu_seqlens[i];
        if (c <= q0) blk_ds = c;
    }
    const int k_begin = blk_ds & ~(BC - 1);
    const int ntiles  = (q0 + BR - 1 - k_begin) / BC + 1;   // block-uniform

    // ---- Q A-frags ----
    short8 aq[4];
    {
        const float* qp = Qh + (size_t)(qw + l16) * HD + quad * 8;
        #pragma unroll
        for (int ks = 0; ks < 4; ++ks) {
            float4 a0 = *(const float4*)(qp + ks * 32);
            float4 a1 = *(const float4*)(qp + ks * 32 + 4);
            short8 a;
            a[0] = bfs(a0.x); a[1] = bfs(a0.y); a[2] = bfs(a0.z); a[3] = bfs(a0.w);
            a[4] = bfs(a1.x); a[5] = bfs(a1.y); a[6] = bfs(a1.z); a[7] = bfs(a1.w);
            aq[ks] = a;
        }
    }

    floatx4 oacc[8];
    #pragma unroll
    for (int dt = 0; dt < 8; ++dt) oacc[dt] = (floatx4){0.f, 0.f, 0.f, 0.f};
    float m_r[4], l_r[4];   // l_r per-lane partials, reduced in epilogue
    #pragma unroll
    for (int r = 0; r < 4; ++r) { m_r[r] = -1e30f; l_r[r] = 0.f; }

    const float sl = 0.08838834764831845f * 1.4426950408889634f;

    // ---- pipeline registers ----
    F4 kf[8];
    float vf[32];

    auto issue_loads = [&](int kt) {
        const float* kb = Kh + (size_t)kt * HD + 4 * dblk;
        #pragma unroll
        for (int p = 0; p < 8; ++p)
            kf[p].v = *(const float4*)(kb + (size_t)(trow + 8 * p) * HD);
        const float* vb = Vh + (size_t)(kt + vhalf * 32) * HD + vd;
        #pragma unroll
        for (int kk = 0; kk < 32; ++kk)
            vf[kk] = vb[(size_t)kk * HD];
    };

    auto write_tiles = [&]() {
        #pragma unroll
        for (int p = 0; p < 8; ++p) {
            uint2 kw;
            kw.x = packbf2(kf[p].f[0], kf[p].f[1]);
            kw.y = packbf2(kf[p].f[2], kf[p].f[3]);
            *(uint2*)(&sK[(trow + 8 * p) * KSTR + 4 * dblk]) = kw;
        }
        unsigned* dst = &sVT[vd * VSTR + vhalf * 16];
        #pragma unroll
        for (int kp = 0; kp < 16; ++kp)
            dst[kp] = packbf2(vf[2 * kp], vf[2 * kp + 1]);
    };

    issue_loads(k_begin);

    __hip_bfloat16* pbuf = &sP[wave][0];

    for (int it = 0; it < ntiles; ++it) {
        const int kt = k_begin + it * BC;

        write_tiles();
        __syncthreads();                         // A: tiles visible

        if (it + 1 < ntiles) issue_loads(kt + BC);

        // ---- S = Q K^T (skip fully-masked 16-key blocks) ----
        floatx4 sc[4];
        #pragma unroll
        for (int ct = 0; ct < 4; ++ct) {
            if (kt + ct * 16 <= qw + 15) {       // wave-uniform
                floatx4 c = (floatx4){0.f, 0.f, 0.f, 0.f};
                #pragma unroll
                for (int ks = 0; ks < 4; ++ks) {
                    short8 b = *(const short8*)(&sK[(ct * 16 + l16) * KSTR + ks * 32 + quad * 8]);
                    c = __builtin_amdgcn_mfma_f32_16x16x32_bf16(aq[ks], b, c, 0, 0, 0);
                }
                const int key = kt + ct * 16 + l16;
                #pragma unroll
                for (int r = 0; r < 4; ++r) {
                    const int q = qw + quad * 4 + r;
                    const bool valid = (key <= q) && (key >= doc_start[r]);
                    float s = c[r] * sl;
                    c[r] = valid ? s : -1e30f;
                }
                sc[ct] = c;
            } else {
                sc[ct] = (floatx4){-1e30f, -1e30f, -1e30f, -1e30f};
            }
        }

        // ---- online softmax: max-reduce only ----
        float mx[4];
        #pragma unroll
        for (int r = 0; r < 4; ++r)
            mx[r] = fmaxf(fmaxf(sc[0][r], sc[1][r]), fmaxf(sc[2][r], sc[3][r]));
        #pragma unroll
        for (int off = 1; off < 16; off <<= 1) {
            #pragma unroll
            for (int r = 0; r < 4; ++r)
                mx[r] = fmaxf(mx[r], __shfl_xor(mx[r], off, 64));
        }
        float al[4];
        #pragma unroll
        for (int r = 0; r < 4; ++r) {
            const float mnew = fmaxf(m_r[r], mx[r]);
            al[r] = exp2f(m_r[r] - mnew);
            m_r[r] = mnew;
        }
        #pragma unroll
        for (int r = 0; r < 4; ++r) {
            float s0 = exp2f(sc[0][r] - m_r[r]);
            float s1 = exp2f(sc[1][r] - m_r[r]);
            float s2 = exp2f(sc[2][r] - m_r[r]);
            float s3 = exp2f(sc[3][r] - m_r[r]);
            sc[0][r] = s0; sc[1][r] = s1; sc[2][r] = s2; sc[3][r] = s3;
            l_r[r] = l_r[r] * al[r] + ((s0 + s1) + (s2 + s3));
        }
        #pragma unroll
        for (int dt = 0; dt < 8; ++dt) {
            #pragma unroll
            for (int r = 0; r < 4; ++r)
                oacc[dt][r] *= al[r];
        }

        // ---- P: C layout -> wave-private LDS -> A layout ----
        #pragma unroll
        for (int ct = 0; ct < 4; ++ct)
            #pragma unroll
            for (int r = 0; r < 4; ++r)
                pbuf[(quad * 4 + r) * PSTR + ct * 16 + l16] = __float2bfloat16(sc[ct][r]);

        // ---- O += P V (skip fully-masked 32-key halves) ----
        #pragma unroll
        for (int ks = 0; ks < 2; ++ks) {
            if (kt + ks * 32 <= qw + 15) {       // wave-uniform
                short4v lo = *(const short4v*)(&pbuf[l16 * PSTR + ks * 32 + quad * 8]);
                short4v hi = *(const short4v*)(&pbuf[l16 * PSTR + ks * 32 + quad * 8 + 4]);
                short8 ap = __builtin_shufflevector(lo, hi, 0, 1, 2, 3, 4, 5, 6, 7);
                #pragma unroll
                for (int dt = 0; dt < 8; ++dt) {
                    const unsigned* vp = &sVT[(dt * 16 + l16) * VSTR + ks * 16 + quad * 4];
                    union { unsigned u[4]; short8 s; } cv;
                    cv.u[0] = vp[0]; cv.u[1] = vp[1]; cv.u[2] = vp[2]; cv.u[3] = vp[3];
                    oacc[dt] = __builtin_amdgcn_mfma_f32_16x16x32_bf16(ap, cv.s, oacc[dt], 0, 0, 0);
                }
            }
        }

        __syncthreads();                         // B: reads done before rewrite
    }

    // ---- epilogue: reduce l over 16 lanes, store ----
    #pragma unroll
    for (int off = 1; off < 16; off <<= 1) {
        #pragma unroll
        for (int r = 0; r < 4; ++r)
            l_r[r] += __shfl_xor(l_r[r], off, 64);
    }
    #pragma unroll
    for (int r = 0; r < 4; ++r) {
        const float inv = 1.0f / l_r[r];
        float* op = Oh + (size_t)(qw + quad * 4 + r) * HD;
        #pragma unroll
        for (int dt = 0; dt < 8; ++dt)
            op[dt * 16 + l16] = oacc[dt][r] * inv;
    }
}

extern "C" void kernel_launch(void* const* d_in, const int* in_sizes, int n_in,
                              void* d_out, int out_size, void* d_ws, size_t ws_size,
                              hipStream_t stream) {
    const float* q = (const float*)d_in[0];
    const float* k = (const float*)d_in[1];
    const float* v = (const float*)d_in[2];
    const int* cu = (const int*)d_in[3];
    const int n_cu = in_sizes[3];
    const int H = 8;
    const int S = in_sizes[0] / (H * HD);   // B=1
    float* out = (float*)d_out;

    dim3 grid(H * (S / BR));   // 512 blocks
    dim3 block(256);
    fa_fwd<<<grid, block, 0, stream>>>(q, k, v, cu, n_cu, out, S);
}

// Round 9
// 132.009 us; speedup vs baseline: 1.3228x; 1.3228x over previous
//
#include <hip/hip_runtime.h>
#include <hip/hip_bf16.h>

// Flash-attention fwd, block-causal packed docs. fp32 HBM, bf16 MFMA.
// B=1, H=8, D=128. 4 waves/block, BR=64, BC=64, grid 512, 2 blocks/CU.
// R7 skeleton: register-prefetch pipeline, DOUBLE-buffered LDS, 1 barrier/tile,
// launch_bounds(256,2) (NOT 3: R8 showed (,3) forces VGPR 84 + ~9MB spill).
// R9: + balanced qb pairing (CU(b)=(b%8 XCD,(b>>3)%32) -> blocks g,g+32 share
// a CU; permute so their ntiles sum to 17, worst-CU work 32->17 tile-units)
// + packed v_cvt_pk_bf16_f32 staging converts.

#define HD 128
#define BR 64
#define BC 64
#define KSTR 136     // bf16 per sK row: 272 B
#define VSTR 33      // dwords per sVT row (32 key-pair dwords + 1 pad; odd)
#define PSTR 68      // bf16 per sP row: 136 B

typedef __attribute__((ext_vector_type(8))) short short8;
typedef __attribute__((ext_vector_type(4))) short short4v;
typedef __attribute__((ext_vector_type(4))) float floatx4;

__device__ inline unsigned packbf2(float lo, float hi) {
    __hip_bfloat162 h2 = __float22bfloat162_rn(make_float2(lo, hi));
    return *reinterpret_cast<unsigned*>(&h2);   // low16 = lo, high16 = hi
}
__device__ inline short bfs(float f) {
    __hip_bfloat16 b = __float2bfloat16(f);
    return *reinterpret_cast<short*>(&b);
}

union F4 { float4 v; float f[4]; };

__global__ __launch_bounds__(256, 2) void fa_fwd(
    const float* __restrict__ Q,
    const float* __restrict__ K,
    const float* __restrict__ V,
    const int* __restrict__ cu_seqlens, int n_cu,
    float* __restrict__ O,
    int S)
{
    __shared__ alignas(16) __hip_bfloat16 sK[2][BC * KSTR];   // 34816 B
    __shared__ alignas(16) unsigned int   sVT[2][HD * VSTR];  // 33792 B
    __shared__ alignas(16) __hip_bfloat16 sP[4][16 * PSTR];   //  8704 B

    const int tid  = threadIdx.x;
    const int wave = tid >> 6;
    const int lane = tid & 63;
    const int quad = lane >> 4;
    const int l16  = lane & 15;

    // K staging coords
    const int dblk = tid & 31;      // d = 4*dblk
    const int trow = tid >> 5;      // 0..7
    // V staging coords: one d-row per thread
    const int vd    = tid & 127;
    const int vhalf = tid >> 7;

    const int nqb = S / BR;
    const int h   = blockIdx.x & 7;
    const int g   = (int)(blockIdx.x >> 3);   // 0..nqb-1
    int qb;
    if (nqb == 64) {
        // balanced pairing: (g, g+32) ntiles sum to 17
        if (g < 32) qb = (g >> 4) * 16 + (15 - (g & 15));        // docs 0,1 desc
        else        qb = 32 + (((g - 32) >> 4) * 16) + (g & 15); // docs 2,3 asc
    } else {
        qb = nqb - 1 - g;
    }
    const int q0  = qb * BR;
    const int qw  = q0 + wave * 16;

    const size_t hoff = (size_t)h * S * HD;
    const float* Qh = Q + hoff;
    const float* Kh = K + hoff;
    const float* Vh = V + hoff;
    float*       Oh = O + hoff;

    // ---- per-row doc starts ----
    int doc_start[4];
    #pragma unroll
    for (int r = 0; r < 4; ++r) {
        const int q = qw + quad * 4 + r;
        int dsr = 0;
        for (int i = 0; i < n_cu; ++i) {
            int c = cu_seqlens[i];
            if (c <= q) dsr = c;
        }
        doc_start[r] = dsr;
    }
    int blk_ds = 0;
    for (int i = 0; i < n_cu; ++i) {
        int c = cu_seqlens[i];
        if (c <= q0) blk_ds = c;
    }
    const int k_begin = blk_ds & ~(BC - 1);
    const int ntiles  = (q0 + BR - 1 - k_begin) / BC + 1;   // block-uniform

    // ---- Q A-frags ----
    short8 aq[4];
    {
        const float* qp = Qh + (size_t)(qw + l16) * HD + quad * 8;
        #pragma unroll
        for (int ks = 0; ks < 4; ++ks) {
            float4 a0 = *(const float4*)(qp + ks * 32);
            float4 a1 = *(const float4*)(qp + ks * 32 + 4);
            short8 a;
            a[0] = bfs(a0.x); a[1] = bfs(a0.y); a[2] = bfs(a0.z); a[3] = bfs(a0.w);
            a[4] = bfs(a1.x); a[5] = bfs(a1.y); a[6] = bfs(a1.z); a[7] = bfs(a1.w);
            aq[ks] = a;
        }
    }

    floatx4 oacc[8];
    #pragma unroll
    for (int dt = 0; dt < 8; ++dt) oacc[dt] = (floatx4){0.f, 0.f, 0.f, 0.f};
    float m_r[4], l_r[4];   // l_r per-lane partials, reduced in epilogue
    #pragma unroll
    for (int r = 0; r < 4; ++r) { m_r[r] = -1e30f; l_r[r] = 0.f; }

    const float sl = 0.08838834764831845f * 1.4426950408889634f;

    // ---- pipeline registers ----
    F4 kf[8];
    float vf[32];

    auto issue_loads = [&](int kt) {
        const float* kb = Kh + (size_t)kt * HD + 4 * dblk;
        #pragma unroll
        for (int p = 0; p < 8; ++p)
            kf[p].v = *(const float4*)(kb + (size_t)(trow + 8 * p) * HD);
        const float* vb = Vh + (size_t)(kt + vhalf * 32) * HD + vd;
        #pragma unroll
        for (int kk = 0; kk < 32; ++kk)
            vf[kk] = vb[(size_t)kk * HD];
    };

    auto write_tiles = [&](int buf) {
        #pragma unroll
        for (int p = 0; p < 8; ++p) {
            uint2 kw;
            kw.x = packbf2(kf[p].f[0], kf[p].f[1]);
            kw.y = packbf2(kf[p].f[2], kf[p].f[3]);
            *(uint2*)(&sK[buf][(trow + 8 * p) * KSTR + 4 * dblk]) = kw;
        }
        unsigned* dst = &sVT[buf][vd * VSTR + vhalf * 16];
        #pragma unroll
        for (int kp = 0; kp < 16; ++kp)
            dst[kp] = packbf2(vf[2 * kp], vf[2 * kp + 1]);
    };

    issue_loads(k_begin);

    __hip_bfloat16* pbuf = &sP[wave][0];

    for (int it = 0; it < ntiles; ++it) {
        const int kt  = k_begin + it * BC;
        const int buf = it & 1;

        write_tiles(buf);
        __syncthreads();                         // one barrier per tile

        if (it + 1 < ntiles) issue_loads(kt + BC);

        // ---- S = Q K^T (skip fully-masked 16-key blocks) ----
        floatx4 sc[4];
        #pragma unroll
        for (int ct = 0; ct < 4; ++ct) {
            if (kt + ct * 16 <= qw + 15) {       // wave-uniform
                floatx4 c = (floatx4){0.f, 0.f, 0.f, 0.f};
                #pragma unroll
                for (int ks = 0; ks < 4; ++ks) {
                    short8 b = *(const short8*)(&sK[buf][(ct * 16 + l16) * KSTR + ks * 32 + quad * 8]);
                    c = __builtin_amdgcn_mfma_f32_16x16x32_bf16(aq[ks], b, c, 0, 0, 0);
                }
                const int key = kt + ct * 16 + l16;
                #pragma unroll
                for (int r = 0; r < 4; ++r) {
                    const int q = qw + quad * 4 + r;
                    const bool valid = (key <= q) && (key >= doc_start[r]);
                    float s = c[r] * sl;
                    c[r] = valid ? s : -1e30f;
                }
                sc[ct] = c;
            } else {
                sc[ct] = (floatx4){-1e30f, -1e30f, -1e30f, -1e30f};
            }
        }

        // ---- online softmax: max-reduce only ----
        float mx[4];
        #pragma unroll
        for (int r = 0; r < 4; ++r)
            mx[r] = fmaxf(fmaxf(sc[0][r], sc[1][r]), fmaxf(sc[2][r], sc[3][r]));
        #pragma unroll
        for (int off = 1; off < 16; off <<= 1) {
            #pragma unroll
            for (int r = 0; r < 4; ++r)
                mx[r] = fmaxf(mx[r], __shfl_xor(mx[r], off, 64));
        }
        float al[4];
        #pragma unroll
        for (int r = 0; r < 4; ++r) {
            const float mnew = fmaxf(m_r[r], mx[r]);
            al[r] = exp2f(m_r[r] - mnew);
            m_r[r] = mnew;
        }
        #pragma unroll
        for (int r = 0; r < 4; ++r) {
            float s0 = exp2f(sc[0][r] - m_r[r]);
            float s1 = exp2f(sc[1][r] - m_r[r]);
            float s2 = exp2f(sc[2][r] - m_r[r]);
            float s3 = exp2f(sc[3][r] - m_r[r]);
            sc[0][r] = s0; sc[1][r] = s1; sc[2][r] = s2; sc[3][r] = s3;
            l_r[r] = l_r[r] * al[r] + ((s0 + s1) + (s2 + s3));
        }
        #pragma unroll
        for (int dt = 0; dt < 8; ++dt) {
            #pragma unroll
            for (int r = 0; r < 4; ++r)
                oacc[dt][r] *= al[r];
        }

        // ---- P: C layout -> wave-private LDS -> A layout ----
        #pragma unroll
        for (int ct = 0; ct < 4; ++ct)
            #pragma unroll
            for (int r = 0; r < 4; ++r)
                pbuf[(quad * 4 + r) * PSTR + ct * 16 + l16] = __float2bfloat16(sc[ct][r]);

        // ---- O += P V (skip fully-masked 32-key halves) ----
        #pragma unroll
        for (int ks = 0; ks < 2; ++ks) {
            if (kt + ks * 32 <= qw + 15) {       // wave-uniform
                short4v lo = *(const short4v*)(&pbuf[l16 * PSTR + ks * 32 + quad * 8]);
                short4v hi = *(const short4v*)(&pbuf[l16 * PSTR + ks * 32 + quad * 8 + 4]);
                short8 ap = __builtin_shufflevector(lo, hi, 0, 1, 2, 3, 4, 5, 6, 7);
                #pragma unroll
                for (int dt = 0; dt < 8; ++dt) {
                    const unsigned* vp = &sVT[buf][(dt * 16 + l16) * VSTR + ks * 16 + quad * 4];
                    union { unsigned u[4]; short8 s; } cv;
                    cv.u[0] = vp[0]; cv.u[1] = vp[1]; cv.u[2] = vp[2]; cv.u[3] = vp[3];
                    oacc[dt] = __builtin_amdgcn_mfma_f32_16x16x32_bf16(ap, cv.s, oacc[dt], 0, 0, 0);
                }
            }
        }
    }

    // ---- epilogue: reduce l over 16 lanes, store ----
    #pragma unroll
    for (int off = 1; off < 16; off <<= 1) {
        #pragma unroll
        for (int r = 0; r < 4; ++r)
            l_r[r] += __shfl_xor(l_r[r], off, 64);
    }
    #pragma unroll
    for (int r = 0; r < 4; ++r) {
        const float inv = 1.0f / l_r[r];
        float* op = Oh + (size_t)(qw + quad * 4 + r) * HD;
        #pragma unroll
        for (int dt = 0; dt < 8; ++dt)
            op[dt * 16 + l16] = oacc[dt][r] * inv;
    }
}

extern "C" void kernel_launch(void* const* d_in, const int* in_sizes, int n_in,
                              void* d_out, int out_size, void* d_ws, size_t ws_size,
                              hipStream_t stream) {
    const float* q = (const float*)d_in[0];
    const float* k = (const float*)d_in[1];
    const float* v = (const float*)d_in[2];
    const int* cu = (const int*)d_in[3];
    const int n_cu = in_sizes[3];
    const int H = 8;
    const int S = in_sizes[0] / (H * HD);   // B=1
    float* out = (float*)d_out;

    dim3 grid(H * (S / BR));   // 512 blocks
    dim3 block(256);
    fa_fwd<<<grid, block, 0, stream>>>(q, k, v, cu, n_cu, out, S);
}